// Round 2
// baseline (324.878 us; speedup 1.0000x reference)
//
#include <hip/hip_runtime.h>

// Problem constants (fixed by setup_inputs)
#define N_ROWS 65536
#define KDIM   256
#define CM     190      // C*M = 19*10
#define CMP    192      // padded to 12 x 16-col tiles
#define KP     512      // concatenated K: [xbar | sqrt_xv]
#define LAMDA  (1.0f/64.0f)
#define LN_EPS 1e-5f

typedef __bf16 bf16;
typedef __attribute__((ext_vector_type(4))) __bf16 bf16x4;
typedef __attribute__((ext_vector_type(8))) __bf16 bf16x8;
typedef __attribute__((ext_vector_type(4))) float  f32x4;

// ---- fast 64-lane reduction: 4 DPP adds (VALU) + xor16 swizzle + xor32 ----
template<int CTRL>
__device__ __forceinline__ float dpp_add(float v) {
    int s = __builtin_amdgcn_update_dpp(0, __builtin_bit_cast(int, v), CTRL, 0xF, 0xF, true);
    return v + __builtin_bit_cast(float, s);
}
__device__ __forceinline__ float wred(float v) {
    v = dpp_add<0xB1>(v);    // quad_perm(1,0,3,2)  : xor 1
    v = dpp_add<0x4E>(v);    // quad_perm(2,3,0,1)  : xor 2
    v = dpp_add<0x141>(v);   // row_half_mirror     : xor 4
    v = dpp_add<0x140>(v);   // row_mirror          : xor 8
    int x = __builtin_amdgcn_ds_swizzle(__builtin_bit_cast(int, v), 0x401F); // xor 16
    v += __builtin_bit_cast(float, x);
    v += __shfl_xor(v, 32, 64);  // xor 32 (cross-half)
    return v;
}

// Fragment chunk index with XOR-ks bank swizzle. Chunk = 16B (8 bf16).
// Reader (phase 2): lane L of (tile, ks) reads chunk(tile, ks, L).
// The XOR spreads writer bank groups 4*((rr^ks)&7) over all 32 banks,
// while for fixed ks it permutes lanes<->addresses bijectively (reads stay
// conflict-free b128).
__device__ __forceinline__ int chunk_idx(int tile, int ks, int L) {
    return (tile * 16 + ks) * 64 + (L ^ (ks & 7));
}

// Store 4 consecutive bf16 (kp 4-aligned) of element-row rr within 16-tile
// `tile` into swizzled MFMA fragment layout.
// Element (rr, kp): ks=kp>>5, kk=kp&31, L = rr | ((kk>>3)<<4), j = kk&7.
__device__ __forceinline__ void frag_store4(bf16* frag, int tile, int rr, int kp,
                                            float a, float b, float c, float d) {
    int ks = kp >> 5;
    int kk = kp & 31;
    int L  = rr | ((kk >> 3) << 4);
    int j  = kk & 7;
    bf16x4 pk;
    pk[0] = (bf16)a; pk[1] = (bf16)b; pk[2] = (bf16)c; pk[3] = (bf16)d;
    *(bf16x4*)(frag + chunk_idx(tile, ks, L) * 8 + j) = pk;
}

// Per-row math for proto_prep (single row per wave; latency irrelevant there).
__device__ __forceinline__ void row_prep(const float4& X, const float4& V,
                                         const float4& E0, const float4& E1,
                                         const float* w, const float* b,
                                         float* xb, float* sx, float& sum_ev) {
    float xx[4] = {X.x, X.y, X.z, X.w};
    float vv[4] = {V.x, V.y, V.z, V.w};
    float e0[4] = {E0.x, E0.y, E0.z, E0.w};
    float e1[4] = {E1.x, E1.y, E1.z, E1.w};
    sum_ev = 0.0f;
#pragma unroll
    for (int t = 0; t < 4; t++) {
        sx[t] = __expf(0.5f * vv[t]);
        sum_ev += sx[t] * sx[t];
    }
    sum_ev = wred(sum_ev);
    xb[0] = xb[1] = xb[2] = xb[3] = 0.0f;
#pragma unroll
    for (int r = 0; r < 2; r++) {
        const float* e = r ? e1 : e0;
        float tt[4], s1 = 0.0f, s2 = 0.0f;
#pragma unroll
        for (int t = 0; t < 4; t++) {
            tt[t] = e[t] * sx[t] + xx[t];
            s1 += tt[t];
            s2 += tt[t] * tt[t];
        }
        s1 = wred(s1); s2 = wred(s2);
        float mu  = s1 * (1.0f / 256.0f);
        float var = s2 * (1.0f / 256.0f) - mu * mu;
        float inv = rsqrtf(var + LN_EPS);
        float y[4], n2 = 0.0f;
#pragma unroll
        for (int t = 0; t < 4; t++) {
            y[t] = (tt[t] - mu) * inv * w[t] + b[t];
            n2 += y[t] * y[t];
        }
        n2 = wred(n2);
        float sc = 1.0f / fmaxf(sqrtf(n2), 1e-12f);
#pragma unroll
        for (int t = 0; t < 4; t++) xb[t] += 0.5f * y[t] * sc;
    }
}

// ---------------- Kernel 1: prototype prep -> B' fragments + bias_cm --------
__global__ void __launch_bounds__(64) proto_prep(
        const float* __restrict__ proto, const float* __restrict__ pvar,
        const float* __restrict__ eps_p, const float* __restrict__ ln_w,
        const float* __restrict__ ln_b, bf16* __restrict__ Bfrag,
        float* __restrict__ bias_cm) {
    int cm = blockIdx.x;            // 0..191 (190,191 are zero pad)
    int lane = threadIdx.x;         // 0..63
    int ct = cm >> 4, rr = cm & 15;
    int k0 = lane * 4;
    if (cm >= CM) {
        frag_store4(Bfrag, ct, rr, k0,       0.f, 0.f, 0.f, 0.f);
        frag_store4(Bfrag, ct, rr, 256 + k0, 0.f, 0.f, 0.f, 0.f);
        if (lane == 0) bias_cm[cm] = 0.0f;
        return;
    }
    size_t roff = (size_t)cm * KDIM + k0;
    float4 P  = *(const float4*)(proto + roff);
    float4 V  = *(const float4*)(pvar + roff);
    float4 E0 = *(const float4*)(eps_p + roff);
    float4 E1 = *(const float4*)(eps_p + (size_t)CM * KDIM + roff);
    float4 Wv = *(const float4*)(ln_w + k0);
    float4 Bv = *(const float4*)(ln_b + k0);
    float w[4] = {Wv.x, Wv.y, Wv.z, Wv.w};
    float b[4] = {Bv.x, Bv.y, Bv.z, Bv.w};
    float pb[4], sx[4], sum_ev;
    row_prep(P, V, E0, E1, w, b, pb, sx, sum_ev);
    frag_store4(Bfrag, ct, rr, k0, 2.f * pb[0], 2.f * pb[1], 2.f * pb[2], 2.f * pb[3]);
    frag_store4(Bfrag, ct, rr, 256 + k0, 2.f * LAMDA * sx[0], 2.f * LAMDA * sx[1],
                2.f * LAMDA * sx[2], 2.f * LAMDA * sx[3]);
    if (lane == 0) bias_cm[cm] = -LAMDA * sum_ev;
}

// ---------------- Kernel 2: fused x-prep + GEMM + epilogue ------------------
__global__ void __launch_bounds__(256, 2) fused_main(
        const float* __restrict__ x, const float* __restrict__ xvar,
        const float* __restrict__ eps_x, const float* __restrict__ ln_w,
        const float* __restrict__ ln_b, const bf16* __restrict__ Bfrag,
        const float* __restrict__ bias_cm, float* __restrict__ out) {
    __shared__ bf16 Afrag[64 * KP];     // 64 KB, swizzled fragment layout
    __shared__ float bias_n_s[64];
    int tid = threadIdx.x;
    int wave = tid >> 6, lane = tid & 63;
    int row0 = blockIdx.x * 64;
    int k0 = lane * 4;
    float4 Wv = *(const float4*)(ln_w + k0);
    float4 Bv = *(const float4*)(ln_b + k0);
    float w[4] = {Wv.x, Wv.y, Wv.z, Wv.w};
    float b[4] = {Bv.x, Bv.y, Bv.z, Bv.w};

    // ---- phase 1: 16 rows per wave, batched 4 at a time for ILP ----
#pragma unroll 1
    for (int batch = 0; batch < 4; batch++) {
        float4 X[4], V[4], E0[4], E1[4];
#pragma unroll
        for (int i = 0; i < 4; i++) {
            int lr = wave * 16 + batch * 4 + i;
            size_t roff = (size_t)(row0 + lr) * KDIM + k0;
            X[i]  = *(const float4*)(x + roff);
            V[i]  = *(const float4*)(xvar + roff);
            E0[i] = *(const float4*)(eps_x + roff);
            E1[i] = *(const float4*)(eps_x + (size_t)N_ROWS * KDIM + roff);
        }
        float sx[4][4], t0[4][4], t1[4][4];
        float s10[4], s20[4], s11[4], s21[4], sev[4];
#pragma unroll
        for (int i = 0; i < 4; i++) {
            float xx[4] = {X[i].x, X[i].y, X[i].z, X[i].w};
            float vv[4] = {V[i].x, V[i].y, V[i].z, V[i].w};
            float e0[4] = {E0[i].x, E0[i].y, E0[i].z, E0[i].w};
            float e1[4] = {E1[i].x, E1[i].y, E1[i].z, E1[i].w};
            sev[i] = 0.f; s10[i] = 0.f; s20[i] = 0.f; s11[i] = 0.f; s21[i] = 0.f;
#pragma unroll
            for (int t = 0; t < 4; t++) {
                float s = __expf(0.5f * vv[t]);
                sx[i][t] = s;
                sev[i] += s * s;
                float a0 = e0[t] * s + xx[t];
                float a1 = e1[t] * s + xx[t];
                t0[i][t] = a0; t1[i][t] = a1;
                s10[i] += a0; s20[i] += a0 * a0;
                s11[i] += a1; s21[i] += a1 * a1;
            }
        }
        // 20 independent reduction chains in flight
#pragma unroll
        for (int i = 0; i < 4; i++) {
            s10[i] = wred(s10[i]); s20[i] = wred(s20[i]);
            s11[i] = wred(s11[i]); s21[i] = wred(s21[i]);
            sev[i] = wred(sev[i]);
        }
        float n20[4], n21[4];
#pragma unroll
        for (int i = 0; i < 4; i++) {
            float mu0  = s10[i] * (1.0f / 256.0f);
            float var0 = s20[i] * (1.0f / 256.0f) - mu0 * mu0;
            float inv0 = rsqrtf(var0 + LN_EPS);
            float mu1  = s11[i] * (1.0f / 256.0f);
            float var1 = s21[i] * (1.0f / 256.0f) - mu1 * mu1;
            float inv1 = rsqrtf(var1 + LN_EPS);
            n20[i] = 0.f; n21[i] = 0.f;
#pragma unroll
            for (int t = 0; t < 4; t++) {
                float y0 = (t0[i][t] - mu0) * inv0 * w[t] + b[t];
                float y1 = (t1[i][t] - mu1) * inv1 * w[t] + b[t];
                t0[i][t] = y0; t1[i][t] = y1;
                n20[i] += y0 * y0;
                n21[i] += y1 * y1;
            }
        }
#pragma unroll
        for (int i = 0; i < 4; i++) { n20[i] = wred(n20[i]); n21[i] = wred(n21[i]); }
#pragma unroll
        for (int i = 0; i < 4; i++) {
            int rr = batch * 4 + i;
            int lr = wave * 16 + rr;
            float sc0 = 1.0f / fmaxf(sqrtf(n20[i]), 1e-12f);
            float sc1 = 1.0f / fmaxf(sqrtf(n21[i]), 1e-12f);
            if (lane == 0) bias_n_s[lr] = -LAMDA * sev[i];
            float xb[4];
#pragma unroll
            for (int t = 0; t < 4; t++)
                xb[t] = 0.5f * (t0[i][t] * sc0 + t1[i][t] * sc1);
            frag_store4(Afrag, wave, rr, k0, xb[0], xb[1], xb[2], xb[3]);
            frag_store4(Afrag, wave, rr, 256 + k0,
                        sx[i][0], sx[i][1], sx[i][2], sx[i][3]);
        }
    }
    __syncthreads();

    // ---- phase 2: GEMM ----
    f32x4 acc[3][4];
#pragma unroll
    for (int c = 0; c < 3; c++)
#pragma unroll
        for (int r = 0; r < 4; r++) acc[c][r] = (f32x4){0.f, 0.f, 0.f, 0.f};

#pragma unroll 2
    for (int ks = 0; ks < 16; ks++) {
        bf16x8 a[4], bb[3];
#pragma unroll
        for (int rt = 0; rt < 4; rt++)
            a[rt] = *(const bf16x8*)(Afrag + chunk_idx(rt, ks, lane) * 8);
#pragma unroll
        for (int ctl = 0; ctl < 3; ctl++)
            bb[ctl] = *(const bf16x8*)(Bfrag + chunk_idx(wave * 3 + ctl, ks, lane) * 8);
#pragma unroll
        for (int ctl = 0; ctl < 3; ctl++)
#pragma unroll
            for (int rt = 0; rt < 4; rt++)
                acc[ctl][rt] = __builtin_amdgcn_mfma_f32_16x16x32_bf16(a[rt], bb[ctl], acc[ctl][rt], 0, 0, 0);
    }

    // ---- epilogue: D layout col=lane&15, row=(lane>>4)*4+reg ----
#pragma unroll
    for (int ctl = 0; ctl < 3; ctl++) {
        int col = wave * 48 + ctl * 16 + (lane & 15);
        float bcm = bias_cm[col];
        bool ok = (col < CM);
#pragma unroll
        for (int rt = 0; rt < 4; rt++) {
            int lr0 = rt * 16 + ((lane >> 4) << 2);
#pragma unroll
            for (int reg = 0; reg < 4; reg++) {
                int lr = lr0 + reg;
                if (ok)
                    out[(size_t)(row0 + lr) * CM + col] =
                        acc[ctl][rt][reg] + bias_n_s[lr] + bcm - 2.0f;
            }
        }
    }
}

extern "C" void kernel_launch(void* const* d_in, const int* in_sizes, int n_in,
                              void* d_out, int out_size, void* d_ws, size_t ws_size,
                              hipStream_t stream) {
    const float* x     = (const float*)d_in[0];
    const float* xvar  = (const float*)d_in[1];
    const float* proto = (const float*)d_in[2];
    const float* pvar  = (const float*)d_in[3];
    const float* eps_x = (const float*)d_in[4];
    const float* eps_p = (const float*)d_in[5];
    const float* ln_w  = (const float*)d_in[6];
    const float* ln_b  = (const float*)d_in[7];
    float* out = (float*)d_out;

    bf16*  Bfrag   = (bf16*)d_ws;                                   // 192*512*2 B
    float* bias_cm = (float*)((char*)d_ws + (size_t)CMP * KP * 2);  // 192 floats

    proto_prep<<<CMP, 64, 0, stream>>>(proto, pvar, eps_p, ln_w, ln_b, Bfrag, bias_cm);
    fused_main<<<N_ROWS / 64, 256, 0, stream>>>(x, xvar, eps_x, ln_w, ln_b, Bfrag, bias_cm, out);
}

// Round 3
// 319.080 us; speedup vs baseline: 1.0182x; 1.0182x over previous
//
#include <hip/hip_runtime.h>

// Problem constants (fixed by setup_inputs)
#define N_ROWS 65536
#define KDIM   256
#define CM     190      // C*M = 19*10
#define CMP    192      // padded to 12 x 16-col tiles
#define KP     512      // concatenated K: [xbar | sqrt_xv]
#define LAMDA  (1.0f/64.0f)
#define LN_EPS 1e-5f

typedef __bf16 bf16;
typedef __attribute__((ext_vector_type(4))) __bf16 bf16x4;
typedef __attribute__((ext_vector_type(8))) __bf16 bf16x8;
typedef __attribute__((ext_vector_type(4))) float  f32x4;

// ---- DPP butterfly pieces ----
template<int CTRL>
__device__ __forceinline__ float dpp_add(float v) {
    int s = __builtin_amdgcn_update_dpp(0, __builtin_bit_cast(int, v), CTRL, 0xF, 0xF, true);
    return v + __builtin_bit_cast(float, s);
}
// sum over each 32-lane group, broadcast within the group
__device__ __forceinline__ float wred32(float v) {
    v = dpp_add<0xB1>(v);    // quad_perm(1,0,3,2): pair xor1
    v = dpp_add<0x4E>(v);    // quad_perm(2,3,0,1): pair xor2
    v = dpp_add<0x141>(v);   // row_half_mirror: pairs quads within 8
    v = dpp_add<0x140>(v);   // row_mirror: pairs 8-halves within 16
    int x = __builtin_amdgcn_ds_swizzle(__builtin_bit_cast(int, v), 0x401F); // xor16 in 32
    return v + __builtin_bit_cast(float, x);
}
// full 64-lane reduction (proto_prep only)
__device__ __forceinline__ float wred64(float v) {
    v = wred32(v);
    return v + __shfl_xor(v, 32, 64);
}

// Fragment chunk index, 16B chunks. Logical chunk lane Lr for (tile, ks) is
// stored at position Lr ^ (ks&7) ^ ((Lr>>3)&7): for any 8 consecutive logical
// lanes the stored low-3 bits are all distinct -> every 8-lane b128 phase
// spans all 32 banks (reads AND phase-1 writes conflict-free).
__device__ __forceinline__ int chunk_idx(int tile, int ks, int L) {
    int p = L ^ (ks & 7) ^ ((L >> 3) & 7);
    return (tile * 16 + ks) * 64 + p;
}

// Store 4 consecutive bf16 of element-row rr, k-offset kp (kp 4-aligned).
// Element (rr, kp): ks=kp>>5, kk=kp&31, Lr = rr + 16*(kk>>3), j = kk&7.
__device__ __forceinline__ void frag_store4(bf16* frag, int tile, int rr, int kp,
                                            float a, float b, float c, float d) {
    int ks = kp >> 5;
    int kk = kp & 31;
    int L  = rr + 16 * (kk >> 3);
    int j  = kk & 7;
    bf16x4 pk;
    pk[0] = (bf16)a; pk[1] = (bf16)b; pk[2] = (bf16)c; pk[3] = (bf16)d;
    *(bf16x4*)(frag + chunk_idx(tile, ks, L) * 8 + j) = pk;
}

// ---------------- Kernel 1: prototype prep -> B' fragments + bias_cm --------
// B'[cm, k<256]  = 2 * pbar[k]
// B'[cm, 256+k]  = 2*lamda*exp(0.5*pv)
// bias_cm[cm]    = -lamda * sum_k exp(pv)
__global__ void __launch_bounds__(64) proto_prep(
        const float* __restrict__ proto, const float* __restrict__ pvar,
        const float* __restrict__ eps_p, const float* __restrict__ ln_w,
        const float* __restrict__ ln_b, bf16* __restrict__ Bfrag,
        float* __restrict__ bias_cm) {
    int cm = blockIdx.x;            // 0..191 (190,191 zero pad)
    int lane = threadIdx.x;
    int ct = cm >> 4, rr = cm & 15;
    int k0 = lane * 4;
    if (cm >= CM) {
        frag_store4(Bfrag, ct, rr, k0,       0.f, 0.f, 0.f, 0.f);
        frag_store4(Bfrag, ct, rr, 256 + k0, 0.f, 0.f, 0.f, 0.f);
        if (lane == 0) bias_cm[cm] = 0.0f;
        return;
    }
    size_t roff = (size_t)cm * KDIM + k0;
    float4 P  = *(const float4*)(proto + roff);
    float4 V  = *(const float4*)(pvar + roff);
    float4 E0 = *(const float4*)(eps_p + roff);
    float4 E1 = *(const float4*)(eps_p + (size_t)CM * KDIM + roff);
    float4 Wv = *(const float4*)(ln_w + k0);
    float4 Bv = *(const float4*)(ln_b + k0);
    float xx[4] = {P.x, P.y, P.z, P.w};
    float vv[4] = {V.x, V.y, V.z, V.w};
    float e0[4] = {E0.x, E0.y, E0.z, E0.w};
    float e1[4] = {E1.x, E1.y, E1.z, E1.w};
    float w[4]  = {Wv.x, Wv.y, Wv.z, Wv.w};
    float b[4]  = {Bv.x, Bv.y, Bv.z, Bv.w};
    float sx[4], sum_ev = 0.f;
#pragma unroll
    for (int t = 0; t < 4; t++) {
        sx[t] = __expf(0.5f * vv[t]);
        sum_ev += sx[t] * sx[t];
    }
    sum_ev = wred64(sum_ev);
    float pb[4] = {0.f, 0.f, 0.f, 0.f};
#pragma unroll
    for (int r = 0; r < 2; r++) {
        const float* e = r ? e1 : e0;
        float tt[4], s1 = 0.f, s2 = 0.f;
#pragma unroll
        for (int t = 0; t < 4; t++) {
            tt[t] = e[t] * sx[t] + xx[t];
            s1 += tt[t]; s2 += tt[t] * tt[t];
        }
        s1 = wred64(s1); s2 = wred64(s2);
        float mu  = s1 * (1.0f / 256.0f);
        float var = s2 * (1.0f / 256.0f) - mu * mu;
        float inv = rsqrtf(var + LN_EPS);
        float y[4], n2 = 0.f;
#pragma unroll
        for (int t = 0; t < 4; t++) {
            y[t] = (tt[t] - mu) * inv * w[t] + b[t];
            n2 += y[t] * y[t];
        }
        n2 = wred64(n2);
        float sc = 1.0f / fmaxf(sqrtf(n2), 1e-12f);
#pragma unroll
        for (int t = 0; t < 4; t++) pb[t] += 0.5f * y[t] * sc;
    }
    frag_store4(Bfrag, ct, rr, k0, 2.f * pb[0], 2.f * pb[1], 2.f * pb[2], 2.f * pb[3]);
    frag_store4(Bfrag, ct, rr, 256 + k0, 2.f * LAMDA * sx[0], 2.f * LAMDA * sx[1],
                2.f * LAMDA * sx[2], 2.f * LAMDA * sx[3]);
    if (lane == 0) bias_cm[cm] = -LAMDA * sum_ev;
}

// ---------------- Kernel 2: fused x-prep + GEMM + epilogue ------------------
// 256 thr (4 waves), 64 rows/block. Phase 1: row spread over 32 lanes
// (8 elems/lane), 2 rows per wave-batch, 8 batches, software-pipelined
// (double-buffered registers). Phase 2: 16x16x32 MFMA, prefetch distance 1.
struct Buf { f32x4 V[2], X[2], E0[2], E1[2]; };

__global__ void __launch_bounds__(256, 2) fused_main(
        const float* __restrict__ x, const float* __restrict__ xvar,
        const float* __restrict__ eps_x, const float* __restrict__ ln_w,
        const float* __restrict__ ln_b, const bf16* __restrict__ Bfrag,
        const float* __restrict__ bias_cm, float* __restrict__ out) {
    __shared__ bf16 Afrag[64 * KP];     // 64 KB
    __shared__ float bias_n_s[64];
    int tid  = threadIdx.x;
    int wave = tid >> 6, lane = tid & 63;
    int sub  = lane & 31;               // position within row (x8 elems)
    int half = lane >> 5;               // which of the 2 rows in a batch
    int row0 = blockIdx.x * 64;
    int rbase = row0 + wave * 16;

    // this lane's 8 LN params (elements sub*8 .. sub*8+7)
    f32x4 w0 = *(const f32x4*)(ln_w + sub * 8);
    f32x4 w1 = *(const f32x4*)(ln_w + sub * 8 + 4);
    f32x4 b0 = *(const f32x4*)(ln_b + sub * 8);
    f32x4 b1 = *(const f32x4*)(ln_b + sub * 8 + 4);

    const size_t eoff = (size_t)N_ROWS * KDIM;

    Buf buf[2];
    auto load_batch = [&](Buf& bf, int batch) {
        size_t roff = (size_t)(rbase + batch * 2 + half) * KDIM + sub * 8;
        bf.V[0]  = *(const f32x4*)(xvar + roff);
        bf.V[1]  = *(const f32x4*)(xvar + roff + 4);
        bf.X[0]  = *(const f32x4*)(x + roff);
        bf.X[1]  = *(const f32x4*)(x + roff + 4);
        bf.E0[0] = *(const f32x4*)(eps_x + roff);
        bf.E0[1] = *(const f32x4*)(eps_x + roff + 4);
        bf.E1[0] = *(const f32x4*)(eps_x + eoff + roff);
        bf.E1[1] = *(const f32x4*)(eps_x + eoff + roff + 4);
    };

    load_batch(buf[0], 0);
#pragma unroll
    for (int batch = 0; batch < 8; batch++) {
        Buf& cb = buf[batch & 1];
        if (batch < 7) load_batch(buf[(batch + 1) & 1], batch + 1);

        float sx[8], t0[8], t1[8];
        float sev = 0.f, s10 = 0.f, s20 = 0.f, s11 = 0.f, s21 = 0.f;
#pragma unroll
        for (int j = 0; j < 2; j++)
#pragma unroll
        for (int t = 0; t < 4; t++) {
            int m = j * 4 + t;
            float s = __expf(0.5f * cb.V[j][t]);
            sx[m] = s;
            sev += s * s;
            float a0 = cb.E0[j][t] * s + cb.X[j][t];
            float a1 = cb.E1[j][t] * s + cb.X[j][t];
            t0[m] = a0; t1[m] = a1;
            s10 += a0; s20 += a0 * a0;
            s11 += a1; s21 += a1 * a1;
        }
        s10 = wred32(s10); s20 = wred32(s20);
        s11 = wred32(s11); s21 = wred32(s21);
        sev = wred32(sev);
        float mu0  = s10 * (1.0f / 256.0f);
        float var0 = s20 * (1.0f / 256.0f) - mu0 * mu0;
        float inv0 = rsqrtf(var0 + LN_EPS);
        float mu1  = s11 * (1.0f / 256.0f);
        float var1 = s21 * (1.0f / 256.0f) - mu1 * mu1;
        float inv1 = rsqrtf(var1 + LN_EPS);
        float n20 = 0.f, n21 = 0.f;
#pragma unroll
        for (int m = 0; m < 8; m++) {
            float wm = (m < 4) ? w0[m & 3] : w1[m & 3];
            float bm = (m < 4) ? b0[m & 3] : b1[m & 3];
            float y0 = (t0[m] - mu0) * inv0 * wm + bm;
            float y1 = (t1[m] - mu1) * inv1 * wm + bm;
            t0[m] = y0; t1[m] = y1;
            n20 += y0 * y0; n21 += y1 * y1;
        }
        n20 = wred32(n20); n21 = wred32(n21);
        float sc0 = 0.5f / fmaxf(sqrtf(n20), 1e-12f);
        float sc1 = 0.5f / fmaxf(sqrtf(n21), 1e-12f);

        int rr = batch * 2 + half;
        if (sub == 0) bias_n_s[wave * 16 + rr] = -LAMDA * sev;

        bf16x8 xp, sp;
#pragma unroll
        for (int m = 0; m < 8; m++) {
            xp[m] = (bf16)(t0[m] * sc0 + t1[m] * sc1);
            sp[m] = (bf16)sx[m];
        }
        int ks = sub >> 2;
        int Lr = rr + 16 * (sub & 3);
        *(bf16x8*)(Afrag + chunk_idx(wave, ks, Lr) * 8)     = xp;
        *(bf16x8*)(Afrag + chunk_idx(wave, 8 + ks, Lr) * 8) = sp;
    }
    __syncthreads();

    // ---- phase 2: GEMM, prefetch distance 1 ----
    f32x4 acc[3][4];
#pragma unroll
    for (int c = 0; c < 3; c++)
#pragma unroll
        for (int r = 0; r < 4; r++) acc[c][r] = (f32x4){0.f, 0.f, 0.f, 0.f};

    bf16x8 aA[2][4], aB[2][3];
    auto loadA = [&](bf16x8* dst, int ks) {
#pragma unroll
        for (int rt = 0; rt < 4; rt++)
            dst[rt] = *(const bf16x8*)(Afrag + chunk_idx(rt, ks, lane) * 8);
    };
    auto loadB = [&](bf16x8* dst, int ks) {
#pragma unroll
        for (int ctl = 0; ctl < 3; ctl++)
            dst[ctl] = *(const bf16x8*)(Bfrag + chunk_idx(wave * 3 + ctl, ks, lane) * 8);
    };
    loadA(aA[0], 0); loadB(aB[0], 0);
#pragma unroll
    for (int ks = 0; ks < 16; ks++) {
        int cur = ks & 1;
        if (ks < 15) { loadB(aB[cur ^ 1], ks + 1); loadA(aA[cur ^ 1], ks + 1); }
#pragma unroll
        for (int ctl = 0; ctl < 3; ctl++)
#pragma unroll
            for (int rt = 0; rt < 4; rt++)
                acc[ctl][rt] = __builtin_amdgcn_mfma_f32_16x16x32_bf16(
                    aA[cur][rt], aB[cur][ctl], acc[ctl][rt], 0, 0, 0);
    }

    // ---- epilogue: D layout col=lane&15, row=(lane>>4)*4+reg ----
#pragma unroll
    for (int ctl = 0; ctl < 3; ctl++) {
        int col = wave * 48 + ctl * 16 + (lane & 15);
        float bcm = (col < CM) ? bias_cm[col] : 0.0f;
        bool ok = (col < CM);
#pragma unroll
        for (int rt = 0; rt < 4; rt++) {
            int lr0 = rt * 16 + ((lane >> 4) << 2);
#pragma unroll
            for (int reg = 0; reg < 4; reg++) {
                int lr = lr0 + reg;
                if (ok)
                    out[(size_t)(row0 + lr) * CM + col] =
                        acc[ctl][rt][reg] + bias_n_s[lr] + bcm - 2.0f;
            }
        }
    }
}

extern "C" void kernel_launch(void* const* d_in, const int* in_sizes, int n_in,
                              void* d_out, int out_size, void* d_ws, size_t ws_size,
                              hipStream_t stream) {
    const float* x     = (const float*)d_in[0];
    const float* xvar  = (const float*)d_in[1];
    const float* proto = (const float*)d_in[2];
    const float* pvar  = (const float*)d_in[3];
    const float* eps_x = (const float*)d_in[4];
    const float* eps_p = (const float*)d_in[5];
    const float* ln_w  = (const float*)d_in[6];
    const float* ln_b  = (const float*)d_in[7];
    float* out = (float*)d_out;

    bf16*  Bfrag   = (bf16*)d_ws;                                   // 192*512*2 B
    float* bias_cm = (float*)((char*)d_ws + (size_t)CMP * KP * 2);  // 192 floats

    proto_prep<<<CMP, 64, 0, stream>>>(proto, pvar, eps_p, ln_w, ln_b, Bfrag, bias_cm);
    fused_main<<<N_ROWS / 64, 256, 0, stream>>>(x, xvar, eps_x, ln_w, ln_b, Bfrag, bias_cm, out);
}